// Round 1
// baseline (1507.584 us; speedup 1.0000x reference)
//
#include <hip/hip_runtime.h>
#include <hip/hip_bf16.h>

// S4D layer: B=16, L=2048, H=512, N=64, fp32.
// Plan: K-table kernel -> transpose (B,L,H)->(B,H,L) -> in-place direct causal
// conv per row (+D skip) -> transpose back.
// Workspace: gK = 512*2048 f32 (4 MB) at ws+0; gut = 16*512*2048 f32 (67 MB) after.

#define BSZ 16
#define LSEQ 2048
#define HCH 512
#define NST 64

__device__ __forceinline__ void sincos_red(float a, float* s, float* c) {
    // accurate sin/cos of the fp32 value a (arbitrary magnitude): reduce mod 2pi in double
    double ad = (double)a;
    double q = rint(ad * 0.15915494309189535);      // a / (2*pi), rounded
    float r = (float)(ad - q * 6.283185307179586);  // |r| <= pi
    __sincosf(r, s, c);
}

// ---------------------------------------------------------------- K table ---
__global__ void k_computeK(const float* __restrict__ lam_r,
                           const float* __restrict__ lam_i,
                           const float* __restrict__ Br,
                           const float* __restrict__ Bi,
                           const float* __restrict__ Cr,
                           const float* __restrict__ Ci,
                           const float* __restrict__ log_dt,
                           float* __restrict__ gK)  // [H][L]
{
    const int h = blockIdx.x;
    const int t = threadIdx.x;  // 256 threads
    __shared__ float sWr[NST], sWi[NST], sAr[NST], sAi[NST], sDr[NST], sDi[NST];

    if (t < NST) {
        const int n = t;
        float lr = lam_r[n], li = lam_i[n];
        float dt = __expf(log_dt[h]);
        float dar = dt * lr;   // fp32 product, same rounding as reference
        float dai = dt * li;
        float e = __expf(dar);
        float sn, cs; sincos_red(dai, &sn, &cs);
        float Ar = e * cs, Ai = e * sn;            // A = exp(dt*Lam)
        // Bb = (Br+iBi)*(A-1)/(lr+1e-8 + i*li)
        float nr = Ar - 1.0f, ni = Ai;
        float br = Br[h * NST + n], bi = Bi[h * NST + n];
        float tr = br * nr - bi * ni;
        float ti = br * ni + bi * nr;
        float dr = lr + 1e-8f, di = li;
        float den = dr * dr + di * di;
        float bbr = (tr * dr + ti * di) / den;
        float bbi = (ti * dr - tr * di) / den;
        // W = (Cr+iCi)*Bb
        float cr = Cr[h * NST + n], ci = Ci[h * NST + n];
        sWr[n] = cr * bbr - ci * bbi;
        sWi[n] = cr * bbi + ci * bbr;
        sAr[n] = Ar; sAi[n] = Ai;
        sDr[n] = dar; sDi[n] = dai;
    }
    __syncthreads();

    const int l0 = t * 8;
    float acc[8];
#pragma unroll
    for (int k = 0; k < 8; ++k) acc[k] = 0.0f;

    const float fl0 = (float)l0;
    for (int n = 0; n < NST; ++n) {
        float dar = sDr[n], dai = sDi[n];
        float ang = dai * fl0;                      // fp32 product like reference
        float sn, cs; sincos_red(ang, &sn, &cs);
        float e = __expf(dar * fl0);
        float pr = e * cs, pi = e * sn;             // p = exp(dtA*l0)
        float Ar = sAr[n], Ai = sAi[n];
        float wr = sWr[n], wi = sWi[n];
#pragma unroll
        for (int k = 0; k < 8; ++k) {
            acc[k] += wr * pr - wi * pi;
            float npr = pr * Ar - pi * Ai;
            pi = pr * Ai + pi * Ar;
            pr = npr;
        }
    }
    float4 o0 = make_float4(acc[0], acc[1], acc[2], acc[3]);
    float4 o1 = make_float4(acc[4], acc[5], acc[6], acc[7]);
    float4* out4 = (float4*)(gK + (size_t)h * LSEQ + l0);
    out4[0] = o0;
    out4[1] = o1;
}

// -------------------------------------------------------------- transposes ---
__global__ void k_transpose_fwd(const float* __restrict__ in,  // (B,L,H)
                                float* __restrict__ out)       // (B,H,L)
{
    __shared__ float tile[32][33];
    const int b  = blockIdx.z;
    const int lt = blockIdx.x * 32;
    const int ht = blockIdx.y * 32;
    const int tx = threadIdx.x;   // 32
    const int ty = threadIdx.y;   // 8
    const float* inb = in + (size_t)b * LSEQ * HCH;
    float* outb = out + (size_t)b * HCH * LSEQ;
#pragma unroll
    for (int i = 0; i < 4; ++i) {
        int l = lt + ty + i * 8;
        tile[ty + i * 8][tx] = inb[(size_t)l * HCH + ht + tx];
    }
    __syncthreads();
#pragma unroll
    for (int i = 0; i < 4; ++i) {
        int hh = ht + ty + i * 8;
        outb[(size_t)hh * LSEQ + lt + tx] = tile[tx][ty + i * 8];
    }
}

__global__ void k_transpose_bwd(const float* __restrict__ in,  // (B,H,L)
                                float* __restrict__ out)       // (B,L,H)
{
    __shared__ float tile[32][33];
    const int b  = blockIdx.z;
    const int lt = blockIdx.x * 32;
    const int ht = blockIdx.y * 32;
    const int tx = threadIdx.x;
    const int ty = threadIdx.y;
    const float* inb = in + (size_t)b * HCH * LSEQ;
    float* outb = out + (size_t)b * LSEQ * HCH;
#pragma unroll
    for (int i = 0; i < 4; ++i) {
        int hh = ht + ty + i * 8;
        tile[ty + i * 8][tx] = inb[(size_t)hh * LSEQ + lt + tx];
    }
    __syncthreads();
#pragma unroll
    for (int i = 0; i < 4; ++i) {
        int l = lt + ty + i * 8;
        outb[(size_t)l * HCH + ht + tx] = tile[tx][ty + i * 8];
    }
}

// ------------------------------------------------------------------- conv ---
// acc[k] += sum_j u[j] * K[l0+k-j], 8 outputs starting at l0 (l0 multiple of 8)
__device__ __forceinline__ void conv_chunk(const float* __restrict__ uS,
                                           const float* __restrict__ kS,
                                           int l0, float acc[8])
{
#pragma unroll
    for (int k = 0; k < 8; ++k) acc[k] = 0.0f;
    int j = 0;
    for (; j + 8 <= l0; j += 8) {
        float4 ua = *(const float4*)(uS + j);
        float4 ub = *(const float4*)(uS + j + 4);
        float uv[8] = {ua.x, ua.y, ua.z, ua.w, ub.x, ub.y, ub.z, ub.w};
        // K window kS[l0-j-8 .. l0-j+7]  (base is multiple of 8, >= 0)
        const float4* kp = (const float4*)(kS + (l0 - j - 8));
        float4 k0 = kp[0], k1 = kp[1], k2 = kp[2], k3 = kp[3];
        float kw[16] = {k0.x, k0.y, k0.z, k0.w, k1.x, k1.y, k1.z, k1.w,
                        k2.x, k2.y, k2.z, k2.w, k3.x, k3.y, k3.z, k3.w};
#pragma unroll
        for (int d = 0; d < 8; ++d) {
            float uvd = uv[d];
#pragma unroll
            for (int k = 0; k < 8; ++k)
                acc[k] += uvd * kw[8 + k - d];
        }
    }
    // tail (<= 15 iterations)
    for (; j <= l0 + 7; ++j) {
        float uvd = uS[j];
#pragma unroll
        for (int k = 0; k < 8; ++k) {
            int d = l0 + k - j;
            if (d >= 0) acc[k] += uvd * kS[d];
        }
    }
}

__global__ __launch_bounds__(128) void k_conv(const float* __restrict__ gK,  // [H][L]
                                              float* __restrict__ gut,       // [B][H][L], in-place
                                              const float* __restrict__ gD)
{
    const int bh = blockIdx.x;          // b*512 + h
    const int h  = bh & (HCH - 1);
    __shared__ float uS[LSEQ];
    __shared__ float kS[LSEQ];
    float* row = gut + (size_t)bh * LSEQ;
    const float* kr = gK + (size_t)h * LSEQ;
    const int t = threadIdx.x;          // 128

#pragma unroll
    for (int i = 0; i < 4; ++i) {
        int idx = t + i * 128;          // float4 index 0..511
        ((float4*)uS)[idx] = ((const float4*)row)[idx];
        ((float4*)kS)[idx] = ((const float4*)kr)[idx];
    }
    __syncthreads();

    const float Dh = gD[h];

    // Two chunks per thread, balanced: work(t) + work(255-t) = const
    const int l0 = 8 * t;
    const int l1 = 8 * (255 - t);
    float acc0[8], acc1[8];
    conv_chunk(uS, kS, l0, acc0);
    conv_chunk(uS, kS, l1, acc1);

    // epilogue: y = conv + D*u ; global row only read during staging -> safe
    float4 o;
    o = make_float4(acc0[0] + Dh * uS[l0 + 0], acc0[1] + Dh * uS[l0 + 1],
                    acc0[2] + Dh * uS[l0 + 2], acc0[3] + Dh * uS[l0 + 3]);
    ((float4*)row)[l0 / 4] = o;
    o = make_float4(acc0[4] + Dh * uS[l0 + 4], acc0[5] + Dh * uS[l0 + 5],
                    acc0[6] + Dh * uS[l0 + 6], acc0[7] + Dh * uS[l0 + 7]);
    ((float4*)row)[l0 / 4 + 1] = o;
    o = make_float4(acc1[0] + Dh * uS[l1 + 0], acc1[1] + Dh * uS[l1 + 1],
                    acc1[2] + Dh * uS[l1 + 2], acc1[3] + Dh * uS[l1 + 3]);
    ((float4*)row)[l1 / 4] = o;
    o = make_float4(acc1[4] + Dh * uS[l1 + 4], acc1[5] + Dh * uS[l1 + 5],
                    acc1[6] + Dh * uS[l1 + 6], acc1[7] + Dh * uS[l1 + 7]);
    ((float4*)row)[l1 / 4 + 1] = o;
}

// ----------------------------------------------------------------- launch ---
extern "C" void kernel_launch(void* const* d_in, const int* in_sizes, int n_in,
                              void* d_out, int out_size, void* d_ws, size_t ws_size,
                              hipStream_t stream)
{
    const float* u      = (const float*)d_in[0];
    const float* lam_r  = (const float*)d_in[1];
    const float* lam_i  = (const float*)d_in[2];
    const float* Br     = (const float*)d_in[3];
    const float* Bi     = (const float*)d_in[4];
    const float* Cr     = (const float*)d_in[5];
    const float* Ci     = (const float*)d_in[6];
    const float* log_dt = (const float*)d_in[7];
    const float* Dv     = (const float*)d_in[8];
    float* out = (float*)d_out;

    float* gK  = (float*)d_ws;                         // 512*2048 f32 = 4 MB
    float* gut = (float*)d_ws + (size_t)HCH * LSEQ;    // 16*512*2048 f32 = 67 MB

    k_computeK<<<HCH, 256, 0, stream>>>(lam_r, lam_i, Br, Bi, Cr, Ci, log_dt, gK);
    k_transpose_fwd<<<dim3(LSEQ / 32, HCH / 32, BSZ), dim3(32, 8, 1), 0, stream>>>(u, gut);
    k_conv<<<BSZ * HCH, 128, 0, stream>>>(gK, gut, Dv);
    k_transpose_bwd<<<dim3(LSEQ / 32, HCH / 32, BSZ), dim3(32, 8, 1), 0, stream>>>(gut, out);
}

// Round 2
// 285.514 us; speedup vs baseline: 5.2802x; 5.2802x over previous
//
#include <hip/hip_runtime.h>
#include <hip/hip_bf16.h>

// S4D layer: B=16, L=2048, H=512, N=64, fp32.
// Round 2: FFT convolution.
//   k_kfft:        per h, compute K row (time domain) in LDS, forward DIF FFT,
//                  store Kf (digit-reversed order) into d_out scratch region.
//   transpose_fwd: (B,L,H) -> (B,H,L) into ws.
//   k_fftconv:     per (b,h) pair rows (b, b+8): z = u0 + i*u1, fwd FFT,
//                  z *= Kf, inv FFT, y = z/N + D*u, in-place on rows.
//   transpose_bwd: (B,H,L) -> (B,L,H) into d_out (overwrites Kf scratch last).
// ws usage: 67.1 MB (gut only). d_out doubles as Kf scratch (16.8 MB) before
// the final transpose writes the real output.

#define BSZ 16
#define LSEQ 2048
#define HCH 512
#define NST 64
#define NF 4096

// LDS padding: +1 word every 32 to break power-of-2 stride bank conflicts
__device__ __forceinline__ int PD(int i) { return i + (i >> 5); }

__device__ __forceinline__ void sincos_red(float a, float* s, float* c) {
    double ad = (double)a;
    double q = rint(ad * 0.15915494309189535);
    float r = (float)(ad - q * 6.283185307179586);
    __sincosf(r, s, c);
}

// In-place radix-4 FFT over LDS re/im (logical length 4096, PD-padded).
// FWD:  DIF, natural input -> digit-reversed output, twiddles e^{-i}.
// !FWD: exact stage-by-stage inverse (conj twiddles, reversed stage order),
//       digit-reversed input -> natural output, unnormalized (x4096).
template <bool FWD>
__device__ __forceinline__ void fft_stages(float* re, float* im,
                                           const float* twc, const float* tws,
                                           int t)
{
    for (int si = 0; si < 6; ++si) {
        const int s   = FWD ? si : 5 - si;
        const int lgQ = 10 - 2 * s;
        const int Q   = 1 << lgQ;
        __syncthreads();
#pragma unroll
        for (int i = 0; i < 4; ++i) {
            const int bb   = t + 256 * i;
            const int j    = bb & (Q - 1);
            const int blk  = bb >> lgQ;
            const int base = (blk << (lgQ + 2)) + j;
            const int i0 = PD(base);
            const int i1 = PD(base + Q);
            const int i2 = PD(base + 2 * Q);
            const int i3 = PD(base + 3 * Q);
            const int k  = j << (2 * s);       // twiddle index into W_4096 table
            const int kp = PD(k);
            float w1r = twc[kp], w1i = tws[kp];
            if (!FWD) w1i = -w1i;
            const float w2r = w1r * w1r - w1i * w1i;
            const float w2i = 2.0f * w1r * w1i;
            const float w3r = w1r * w2r - w1i * w2i;
            const float w3i = w1r * w2i + w1i * w2r;
            float a0r = re[i0], a0i = im[i0];
            float a1r = re[i1], a1i = im[i1];
            float a2r = re[i2], a2i = im[i2];
            float a3r = re[i3], a3i = im[i3];
            if (FWD) {
                float t0r = a0r + a2r, t0i = a0i + a2i;
                float t1r = a0r - a2r, t1i = a0i - a2i;
                float t2r = a1r + a3r, t2i = a1i + a3i;
                float t3r = a1r - a3r, t3i = a1i - a3i;
                float y0r = t0r + t2r, y0i = t0i + t2i;
                float y2r = t0r - t2r, y2i = t0i - t2i;
                float y1r = t1r + t3i, y1i = t1i - t3r;   // t1 - i*t3
                float y3r = t1r - t3i, y3i = t1i + t3r;   // t1 + i*t3
                re[i0] = y0r;                     im[i0] = y0i;
                re[i1] = y1r * w1r - y1i * w1i;   im[i1] = y1r * w1i + y1i * w1r;
                re[i2] = y2r * w2r - y2i * w2i;   im[i2] = y2r * w2i + y2i * w2r;
                re[i3] = y3r * w3r - y3i * w3i;   im[i3] = y3r * w3i + y3i * w3r;
            } else {
                // undo: b_r = stored_r * conj(W)^{r j}, then inverse DFT4 (+i)
                float b1r = a1r * w1r - a1i * w1i, b1i = a1r * w1i + a1i * w1r;
                float b2r = a2r * w2r - a2i * w2i, b2i = a2r * w2i + a2i * w2r;
                float b3r = a3r * w3r - a3i * w3i, b3i = a3r * w3i + a3i * w3r;
                float t0r = a0r + b2r, t0i = a0i + b2i;
                float t1r = a0r - b2r, t1i = a0i - b2i;
                float t2r = b1r + b3r, t2i = b1i + b3i;
                float t3r = b1r - b3r, t3i = b1i - b3i;
                re[i0] = t0r + t2r;  im[i0] = t0i + t2i;
                re[i2] = t0r - t2r;  im[i2] = t0i - t2i;
                re[i1] = t1r - t3i;  im[i1] = t1i + t3r;  // t1 + i*t3
                re[i3] = t1r + t3i;  im[i3] = t1i - t3r;  // t1 - i*t3
            }
        }
    }
}

__device__ __forceinline__ void build_twiddles(float* twc, float* tws, int t) {
#pragma unroll
    for (int i = 0; i < 4; ++i) {
        int r = t + 256 * i;                      // 0..1023
        float sn, cs;
        __sincosf(-1.5339807878856412e-3f * (float)r, &sn, &cs);  // -2*pi/4096 * r
        twc[PD(r)] = cs;
        tws[PD(r)] = sn;
    }
}

// ------------------------------------------------- K table + forward FFT ---
__global__ __launch_bounds__(256) void k_kfft(const float* __restrict__ lam_r,
                                              const float* __restrict__ lam_i,
                                              const float* __restrict__ Br,
                                              const float* __restrict__ Bi,
                                              const float* __restrict__ Cr,
                                              const float* __restrict__ Ci,
                                              const float* __restrict__ log_dt,
                                              float* __restrict__ gKf)  // [H][4096] float2
{
    const int h = blockIdx.x;
    const int t = threadIdx.x;  // 256
    __shared__ float re[4224], im[4224], twc[1056], tws[1056];
    __shared__ float sWr[NST], sWi[NST], sAr[NST], sAi[NST], sDr[NST], sDi[NST];

    build_twiddles(twc, tws, t);

    if (t < NST) {
        const int n = t;
        float lr = lam_r[n], li = lam_i[n];
        float dt = __expf(log_dt[h]);
        float dar = dt * lr;
        float dai = dt * li;
        float e = __expf(dar);
        float sn, cs; sincos_red(dai, &sn, &cs);
        float Ar = e * cs, Ai = e * sn;            // A = exp(dt*Lam)
        float nr = Ar - 1.0f, ni = Ai;
        float br = Br[h * NST + n], bi = Bi[h * NST + n];
        float tr = br * nr - bi * ni;
        float ti = br * ni + bi * nr;
        float dr = lr + 1e-8f, di = li;
        float den = dr * dr + di * di;
        float bbr = (tr * dr + ti * di) / den;
        float bbi = (ti * dr - tr * di) / den;
        float cr = Cr[h * NST + n], ci = Ci[h * NST + n];
        sWr[n] = cr * bbr - ci * bbi;
        sWi[n] = cr * bbi + ci * bbr;
        sAr[n] = Ar; sAi[n] = Ai;
        sDr[n] = dar; sDi[n] = dai;
    }
    __syncthreads();

    // K[l0..l0+7] for l0 = 8t
    const int l0 = t * 8;
    float acc[8];
#pragma unroll
    for (int k = 0; k < 8; ++k) acc[k] = 0.0f;
    const float fl0 = (float)l0;
    for (int n = 0; n < NST; ++n) {
        float dar = sDr[n], dai = sDi[n];
        float ang = dai * fl0;
        float sn, cs; sincos_red(ang, &sn, &cs);
        float e = __expf(dar * fl0);
        float pr = e * cs, pi = e * sn;
        float Ar = sAr[n], Ai = sAi[n];
        float wr = sWr[n], wi = sWi[n];
#pragma unroll
        for (int k = 0; k < 8; ++k) {
            acc[k] += wr * pr - wi * pi;
            float npr = pr * Ar - pi * Ai;
            pi = pr * Ai + pi * Ar;
            pr = npr;
        }
    }
#pragma unroll
    for (int k = 0; k < 8; ++k) {
        re[PD(l0 + k)] = acc[k];
        im[PD(l0 + k)] = 0.0f;
        re[PD(LSEQ + l0 + k)] = 0.0f;   // zero-pad upper half
        im[PD(LSEQ + l0 + k)] = 0.0f;
    }

    fft_stages<true>(re, im, twc, tws, t);
    __syncthreads();

    float2* out = (float2*)gKf + (size_t)h * NF;
#pragma unroll
    for (int i = 0; i < 16; ++i) {
        int idx = t + 256 * i;
        int p = PD(idx);
        out[idx] = make_float2(re[p], im[p]);
    }
}

// -------------------------------------------------------------- transposes ---
__global__ void k_transpose_fwd(const float* __restrict__ in,  // (B,L,H)
                                float* __restrict__ out)       // (B,H,L)
{
    __shared__ float tile[32][33];
    const int b  = blockIdx.z;
    const int lt = blockIdx.x * 32;
    const int ht = blockIdx.y * 32;
    const int tx = threadIdx.x;
    const int ty = threadIdx.y;
    const float* inb = in + (size_t)b * LSEQ * HCH;
    float* outb = out + (size_t)b * HCH * LSEQ;
#pragma unroll
    for (int i = 0; i < 4; ++i) {
        int l = lt + ty + i * 8;
        tile[ty + i * 8][tx] = inb[(size_t)l * HCH + ht + tx];
    }
    __syncthreads();
#pragma unroll
    for (int i = 0; i < 4; ++i) {
        int hh = ht + ty + i * 8;
        outb[(size_t)hh * LSEQ + lt + tx] = tile[tx][ty + i * 8];
    }
}

__global__ void k_transpose_bwd(const float* __restrict__ in,  // (B,H,L)
                                float* __restrict__ out)       // (B,L,H)
{
    __shared__ float tile[32][33];
    const int b  = blockIdx.z;
    const int lt = blockIdx.x * 32;
    const int ht = blockIdx.y * 32;
    const int tx = threadIdx.x;
    const int ty = threadIdx.y;
    const float* inb = in + (size_t)b * HCH * LSEQ;
    float* outb = out + (size_t)b * LSEQ * HCH;
#pragma unroll
    for (int i = 0; i < 4; ++i) {
        int hh = ht + ty + i * 8;
        tile[ty + i * 8][tx] = inb[(size_t)hh * LSEQ + lt + tx];
    }
    __syncthreads();
#pragma unroll
    for (int i = 0; i < 4; ++i) {
        int l = lt + ty + i * 8;
        outb[(size_t)l * HCH + ht + tx] = tile[tx][ty + i * 8];
    }
}

// ----------------------------------------------------------- FFT convolve ---
// One block per (b in 0..7, h): rows (b,h) and (b+8,h) packed as re/im.
__global__ __launch_bounds__(256) void k_fftconv(float* __restrict__ gut,       // [B][H][L]
                                                 const float* __restrict__ gKf, // [H][4096] float2
                                                 const float* __restrict__ gD)
{
    const int bid = blockIdx.x;        // 4096
    const int b = bid >> 9;            // 0..7
    const int h = bid & (HCH - 1);
    const int t = threadIdx.x;         // 256
    __shared__ float re[4224], im[4224], twc[1056], tws[1056];

    float* row0 = gut + ((size_t)(b * HCH) + h) * LSEQ;
    float* row1 = gut + ((size_t)((b + 8) * HCH) + h) * LSEQ;

    build_twiddles(twc, tws, t);

    float4 u0k[2], u1k[2];
#pragma unroll
    for (int i = 0; i < 2; ++i) {
        int q = t + 256 * i;           // float4 index 0..511
        u0k[i] = ((const float4*)row0)[q];
        u1k[i] = ((const float4*)row1)[q];
        int l = 4 * q;
        re[PD(l + 0)] = u0k[i].x;  im[PD(l + 0)] = u1k[i].x;
        re[PD(l + 1)] = u0k[i].y;  im[PD(l + 1)] = u1k[i].y;
        re[PD(l + 2)] = u0k[i].z;  im[PD(l + 2)] = u1k[i].z;
        re[PD(l + 3)] = u0k[i].w;  im[PD(l + 3)] = u1k[i].w;
    }
#pragma unroll
    for (int i = 0; i < 2; ++i) {
        int l = 4 * (t + 256 * i) + LSEQ;   // zero-pad 2048..4095
        re[PD(l + 0)] = 0.0f;  im[PD(l + 0)] = 0.0f;
        re[PD(l + 1)] = 0.0f;  im[PD(l + 1)] = 0.0f;
        re[PD(l + 2)] = 0.0f;  im[PD(l + 2)] = 0.0f;
        re[PD(l + 3)] = 0.0f;  im[PD(l + 3)] = 0.0f;
    }

    fft_stages<true>(re, im, twc, tws, t);
    __syncthreads();

    // pointwise multiply by Kf (both in the same digit-reversed order)
    const float2* kf = (const float2*)gKf + (size_t)h * NF;
#pragma unroll
    for (int i = 0; i < 16; ++i) {
        int idx = t + 256 * i;
        float2 kv = kf[idx];
        int p = PD(idx);
        float zr = re[p], zi = im[p];
        re[p] = zr * kv.x - zi * kv.y;
        im[p] = zr * kv.y + zi * kv.x;
    }

    fft_stages<false>(re, im, twc, tws, t);
    __syncthreads();

    const float sc = 1.0f / 4096.0f;
    const float Dh = gD[h];
#pragma unroll
    for (int i = 0; i < 2; ++i) {
        int q = t + 256 * i;
        int l = 4 * q;
        float4 o0, o1;
        o0.x = re[PD(l + 0)] * sc + Dh * u0k[i].x;  o1.x = im[PD(l + 0)] * sc + Dh * u1k[i].x;
        o0.y = re[PD(l + 1)] * sc + Dh * u0k[i].y;  o1.y = im[PD(l + 1)] * sc + Dh * u1k[i].y;
        o0.z = re[PD(l + 2)] * sc + Dh * u0k[i].z;  o1.z = im[PD(l + 2)] * sc + Dh * u1k[i].z;
        o0.w = re[PD(l + 3)] * sc + Dh * u0k[i].w;  o1.w = im[PD(l + 3)] * sc + Dh * u1k[i].w;
        ((float4*)row0)[q] = o0;
        ((float4*)row1)[q] = o1;
    }
}

// ----------------------------------------------------------------- launch ---
extern "C" void kernel_launch(void* const* d_in, const int* in_sizes, int n_in,
                              void* d_out, int out_size, void* d_ws, size_t ws_size,
                              hipStream_t stream)
{
    const float* u      = (const float*)d_in[0];
    const float* lam_r  = (const float*)d_in[1];
    const float* lam_i  = (const float*)d_in[2];
    const float* Br     = (const float*)d_in[3];
    const float* Bi     = (const float*)d_in[4];
    const float* Cr     = (const float*)d_in[5];
    const float* Ci     = (const float*)d_in[6];
    const float* log_dt = (const float*)d_in[7];
    const float* Dv     = (const float*)d_in[8];

    float* gut = (float*)d_ws;     // 16*512*2048 f32 = 67.1 MB
    float* gKf = (float*)d_out;    // Kf scratch: 512*4096*2 f32 = 16.8 MB,
                                   // overwritten by transpose_bwd at the end

    k_kfft<<<HCH, 256, 0, stream>>>(lam_r, lam_i, Br, Bi, Cr, Ci, log_dt, gKf);
    k_transpose_fwd<<<dim3(LSEQ / 32, HCH / 32, BSZ), dim3(32, 8, 1), 0, stream>>>(u, gut);
    k_fftconv<<<BSZ / 2 * HCH, 256, 0, stream>>>(gut, gKf, Dv);
    k_transpose_bwd<<<dim3(LSEQ / 32, HCH / 32, BSZ), dim3(32, 8, 1), 0, stream>>>(gut, (float*)d_out);
}

// Round 3
// 244.380 us; speedup vs baseline: 6.1690x; 1.1683x over previous
//
#include <hip/hip_runtime.h>
#include <hip/hip_bf16.h>

// S4D layer: B=16, L=2048, H=512, N=64, fp32.
// Round 3: radix-8 FFT conv, interleaved complex float2 in LDS (b64 ops),
// fused middle (fwd stage3 + pointwise Kf + inv stage3 in registers),
// zero-pad folded into fwd stage0, upper-half stores skipped in inv stage0,
// float4-both-sides transposes.

#define BSZ 16
#define LSEQ 2048
#define HCH 512
#define NST 64
#define NF 4096

// complex i -> word offset (pad 2 words every 16 complex)
__device__ __forceinline__ int WD(int i) { return 2 * i + ((i >> 4) << 1); }

__device__ __forceinline__ float2 cadd(float2 a, float2 b) { return make_float2(a.x + b.x, a.y + b.y); }
__device__ __forceinline__ float2 csub(float2 a, float2 b) { return make_float2(a.x - b.x, a.y - b.y); }
__device__ __forceinline__ float2 cmul(float2 a, float c, float s) {
    return make_float2(a.x * c - a.y * s, a.x * s + a.y * c);
}
__device__ __forceinline__ float2 cmul2(float2 a, float2 b) {
    return make_float2(a.x * b.x - a.y * b.y, a.x * b.y + a.y * b.x);
}

__device__ __forceinline__ void sincos_red(float a, float* s, float* c) {
    double ad = (double)a;
    double q = rint(ad * 0.15915494309189535);
    float r = (float)(ad - q * 6.283185307179586);
    __sincosf(r, s, c);
}

// 8-pt DFT tail: inputs t0..t3 (even part), t4..t7 (odd part, pre-twiddle-free),
// outputs A0..A7.  INV = conjugate transform (+i).
template <bool INV>
__device__ __forceinline__ void dft8_tail(float2 t0, float2 t1, float2 t2, float2 t3,
                                          float2 t4, float2 t5, float2 t6, float2 t7,
                                          float2& A0, float2& A1, float2& A2, float2& A3,
                                          float2& A4, float2& A5, float2& A6, float2& A7)
{
    const float S = 0.70710678118654752f;
    float2 u0 = cadd(t0, t2), u2 = csub(t0, t2);
    float2 u1 = cadd(t1, t3), u3 = csub(t1, t3);
    A0 = cadd(u0, u1); A4 = csub(u0, u1);
    if constexpr (!INV) {
        A2 = make_float2(u2.x + u3.y, u2.y - u3.x);   // u2 - i*u3
        A6 = make_float2(u2.x - u3.y, u2.y + u3.x);
    } else {
        A2 = make_float2(u2.x - u3.y, u2.y + u3.x);   // u2 + i*u3
        A6 = make_float2(u2.x + u3.y, u2.y - u3.x);
    }
    float2 b0 = t4, b1, b2, b3;
    if constexpr (!INV) {
        b1 = make_float2(S * (t5.x + t5.y), S * (t5.y - t5.x));   // t5*W8^1
        b2 = make_float2(t6.y, -t6.x);                            // -i*t6
        b3 = make_float2(S * (t7.y - t7.x), -S * (t7.x + t7.y));  // t7*W8^3
    } else {
        b1 = make_float2(S * (t5.x - t5.y), S * (t5.y + t5.x));   // t5*W8^-1
        b2 = make_float2(-t6.y, t6.x);                            // +i*t6
        b3 = make_float2(-S * (t7.x + t7.y), S * (t7.x - t7.y));  // t7*W8^-3
    }
    float2 v0 = cadd(b0, b2), v2 = csub(b0, b2);
    float2 v1 = cadd(b1, b3), v3 = csub(b1, b3);
    A1 = cadd(v0, v1); A5 = csub(v0, v1);
    if constexpr (!INV) {
        A3 = make_float2(v2.x + v3.y, v2.y - v3.x);
        A7 = make_float2(v2.x - v3.y, v2.y + v3.x);
    } else {
        A3 = make_float2(v2.x - v3.y, v2.y + v3.x);
        A7 = make_float2(v2.x + v3.y, v2.y - v3.x);
    }
}

// One radix-8 stage over LDS z (4096 complex, WD-padded).
// FWD: DIF butterfly, post-twiddle W_4096^{j*r*8^SIDX}.
// INV: pre-twiddle conj, inverse DFT8 (exact stage inverse, x8).
// HALF && !INV : inputs 4..7 are zero (zero-padded upper half) -- skip loads.
// HALF &&  INV : outputs 4..7 not needed -- skip stores.
template <int SIDX, bool INV, bool HALF>
__device__ __forceinline__ void fft8_stage(float* z, int t)
{
    constexpr int lgQ = 9 - 3 * SIDX;
    constexpr int Q = 1 << lgQ;
    const float asc = -1.5339807878856412e-3f * (float)(1 << (3 * SIDX)); // -2pi/4096*8^s
#pragma unroll
    for (int it = 0; it < 2; ++it) {
        const int bb = t + 256 * it;
        const int j = bb & (Q - 1);
        const int base = ((bb >> lgQ) << (lgQ + 3)) + j;
        float s1, c1;
        __sincosf(asc * (float)j, &s1, &c1);
        if constexpr (INV) s1 = -s1;
        const float c2 = c1 * c1 - s1 * s1, s2 = 2.f * c1 * s1;
        const float c3 = c1 * c2 - s1 * s2, s3 = c1 * s2 + s1 * c2;
        const float c4 = c2 * c2 - s2 * s2, s4 = 2.f * c2 * s2;
        const float c5 = c2 * c3 - s2 * s3, s5 = c2 * s3 + s2 * c3;
        const float c6 = c3 * c3 - s3 * s3, s6 = 2.f * c3 * s3;
        const float c7 = c3 * c4 - s3 * s4, s7 = c3 * s4 + s3 * c4;
        float2 a0 = *(float2*)&z[WD(base + 0 * Q)];
        float2 a1 = *(float2*)&z[WD(base + 1 * Q)];
        float2 a2 = *(float2*)&z[WD(base + 2 * Q)];
        float2 a3 = *(float2*)&z[WD(base + 3 * Q)];
        float2 a4, a5, a6, a7;
        if constexpr (!(HALF && !INV)) {
            a4 = *(float2*)&z[WD(base + 4 * Q)];
            a5 = *(float2*)&z[WD(base + 5 * Q)];
            a6 = *(float2*)&z[WD(base + 6 * Q)];
            a7 = *(float2*)&z[WD(base + 7 * Q)];
        }
        if constexpr (INV) {
            a1 = cmul(a1, c1, s1); a2 = cmul(a2, c2, s2); a3 = cmul(a3, c3, s3);
            a4 = cmul(a4, c4, s4); a5 = cmul(a5, c5, s5); a6 = cmul(a6, c6, s6);
            a7 = cmul(a7, c7, s7);
        }
        float2 t0, t1, t2, t3, t4, t5, t6, t7;
        if constexpr (HALF && !INV) {
            t0 = a0; t4 = a0; t1 = a1; t5 = a1; t2 = a2; t6 = a2; t3 = a3; t7 = a3;
        } else {
            t0 = cadd(a0, a4); t4 = csub(a0, a4);
            t1 = cadd(a1, a5); t5 = csub(a1, a5);
            t2 = cadd(a2, a6); t6 = csub(a2, a6);
            t3 = cadd(a3, a7); t7 = csub(a3, a7);
        }
        float2 A0, A1, A2, A3, A4, A5, A6, A7;
        dft8_tail<INV>(t0, t1, t2, t3, t4, t5, t6, t7, A0, A1, A2, A3, A4, A5, A6, A7);
        if constexpr (!INV) {
            A1 = cmul(A1, c1, s1); A2 = cmul(A2, c2, s2); A3 = cmul(A3, c3, s3);
            A4 = cmul(A4, c4, s4); A5 = cmul(A5, c5, s5); A6 = cmul(A6, c6, s6);
            A7 = cmul(A7, c7, s7);
        }
        *(float2*)&z[WD(base + 0 * Q)] = A0;
        *(float2*)&z[WD(base + 1 * Q)] = A1;
        *(float2*)&z[WD(base + 2 * Q)] = A2;
        *(float2*)&z[WD(base + 3 * Q)] = A3;
        if constexpr (!(HALF && INV)) {
            *(float2*)&z[WD(base + 4 * Q)] = A4;
            *(float2*)&z[WD(base + 5 * Q)] = A5;
            *(float2*)&z[WD(base + 6 * Q)] = A6;
            *(float2*)&z[WD(base + 7 * Q)] = A7;
        }
    }
}

// fused: fwd stage3 (Q=1, twiddles=1) + pointwise *Kf + inv stage3, in registers
__device__ __forceinline__ void mid_stage(float* z, const float2* __restrict__ kf, int t)
{
#pragma unroll
    for (int it = 0; it < 2; ++it) {
        const int bb = t + 256 * it;
        const int base = bb * 8;
        float2 a[8];
#pragma unroll
        for (int r = 0; r < 8; ++r) a[r] = *(float2*)&z[WD(base + r)];
        float2 t0 = cadd(a[0], a[4]), t4 = csub(a[0], a[4]);
        float2 t1 = cadd(a[1], a[5]), t5 = csub(a[1], a[5]);
        float2 t2 = cadd(a[2], a[6]), t6 = csub(a[2], a[6]);
        float2 t3 = cadd(a[3], a[7]), t7 = csub(a[3], a[7]);
        float2 A0, A1, A2, A3, A4, A5, A6, A7;
        dft8_tail<false>(t0, t1, t2, t3, t4, t5, t6, t7, A0, A1, A2, A3, A4, A5, A6, A7);
        const float2* kp = kf + base;
        A0 = cmul2(A0, kp[0]); A1 = cmul2(A1, kp[1]);
        A2 = cmul2(A2, kp[2]); A3 = cmul2(A3, kp[3]);
        A4 = cmul2(A4, kp[4]); A5 = cmul2(A5, kp[5]);
        A6 = cmul2(A6, kp[6]); A7 = cmul2(A7, kp[7]);
        t0 = cadd(A0, A4); t4 = csub(A0, A4);
        t1 = cadd(A1, A5); t5 = csub(A1, A5);
        t2 = cadd(A2, A6); t6 = csub(A2, A6);
        t3 = cadd(A3, A7); t7 = csub(A3, A7);
        float2 X0, X1, X2, X3, X4, X5, X6, X7;
        dft8_tail<true>(t0, t1, t2, t3, t4, t5, t6, t7, X0, X1, X2, X3, X4, X5, X6, X7);
        *(float2*)&z[WD(base + 0)] = X0;
        *(float2*)&z[WD(base + 1)] = X1;
        *(float2*)&z[WD(base + 2)] = X2;
        *(float2*)&z[WD(base + 3)] = X3;
        *(float2*)&z[WD(base + 4)] = X4;
        *(float2*)&z[WD(base + 5)] = X5;
        *(float2*)&z[WD(base + 6)] = X6;
        *(float2*)&z[WD(base + 7)] = X7;
    }
}

// ------------------------------------------------- K table + forward FFT ---
__global__ __launch_bounds__(256) void k_kfft(const float* __restrict__ lam_r,
                                              const float* __restrict__ lam_i,
                                              const float* __restrict__ Br,
                                              const float* __restrict__ Bi,
                                              const float* __restrict__ Cr,
                                              const float* __restrict__ Ci,
                                              const float* __restrict__ log_dt,
                                              float* __restrict__ gKf)  // [H][4096] float2
{
    const int h = blockIdx.x;
    const int t = threadIdx.x;  // 256
    __shared__ float z[8704];
    __shared__ float sWr[NST], sWi[NST], sAr[NST], sAi[NST], sDr[NST], sDi[NST];

    if (t < NST) {
        const int n = t;
        float lr = lam_r[n], li = lam_i[n];
        float dt = __expf(log_dt[h]);
        float dar = dt * lr;
        float dai = dt * li;
        float e = __expf(dar);
        float sn, cs; sincos_red(dai, &sn, &cs);
        float Ar = e * cs, Ai = e * sn;
        float nr = Ar - 1.0f, ni = Ai;
        float br = Br[h * NST + n], bi = Bi[h * NST + n];
        float tr = br * nr - bi * ni;
        float ti = br * ni + bi * nr;
        float dr = lr + 1e-8f, di = li;
        float den = dr * dr + di * di;
        float bbr = (tr * dr + ti * di) / den;
        float bbi = (ti * dr - tr * di) / den;
        float cr = Cr[h * NST + n], ci = Ci[h * NST + n];
        sWr[n] = cr * bbr - ci * bbi;
        sWi[n] = cr * bbi + ci * bbr;
        sAr[n] = Ar; sAi[n] = Ai;
        sDr[n] = dar; sDi[n] = dai;
    }
    __syncthreads();

    const int l0 = t * 8;
    float acc[8];
#pragma unroll
    for (int k = 0; k < 8; ++k) acc[k] = 0.0f;
    const float fl0 = (float)l0;
    for (int n = 0; n < NST; ++n) {
        float dar = sDr[n], dai = sDi[n];
        float ang = dai * fl0;
        float sn, cs; sincos_red(ang, &sn, &cs);
        float e = __expf(dar * fl0);
        float pr = e * cs, pi = e * sn;
        float Ar = sAr[n], Ai = sAi[n];
        float wr = sWr[n], wi = sWi[n];
#pragma unroll
        for (int k = 0; k < 8; ++k) {
            acc[k] += wr * pr - wi * pi;
            float npr = pr * Ar - pi * Ai;
            pi = pr * Ai + pi * Ar;
            pr = npr;
        }
    }
#pragma unroll
    for (int k = 0; k < 8; ++k)
        *(float2*)&z[WD(l0 + k)] = make_float2(acc[k], 0.0f);   // lower half only
    __syncthreads();

    fft8_stage<0, false, true >(z, t); __syncthreads();
    fft8_stage<1, false, false>(z, t); __syncthreads();
    fft8_stage<2, false, false>(z, t); __syncthreads();
    fft8_stage<3, false, false>(z, t); __syncthreads();

    float2* out = (float2*)gKf + (size_t)h * NF;
#pragma unroll
    for (int i = 0; i < 16; ++i) {
        int idx = t + 256 * i;
        out[idx] = *(float2*)&z[WD(idx)];
    }
}

// -------------------------------------------------------------- transposes ---
__global__ __launch_bounds__(256) void k_transpose_fwd(const float* __restrict__ in,  // (B,L,H)
                                                       float* __restrict__ out)       // (B,H,L)
{
    __shared__ float tile[32][33];
    const int b  = blockIdx.z;
    const int lt = blockIdx.x * 32;
    const int ht = blockIdx.y * 32;
    const int tx = threadIdx.x;   // 8  (float4 over h)
    const int ty = threadIdx.y;   // 32 (rows)
    const float* inb = in + (size_t)b * LSEQ * HCH;
    float* outb = out + (size_t)b * HCH * LSEQ;
    float4 v = *(const float4*)&inb[(size_t)(lt + ty) * HCH + ht + 4 * tx];
    tile[ty][4 * tx + 0] = v.x;
    tile[ty][4 * tx + 1] = v.y;
    tile[ty][4 * tx + 2] = v.z;
    tile[ty][4 * tx + 3] = v.w;
    __syncthreads();
    float4 o = make_float4(tile[4 * tx + 0][ty], tile[4 * tx + 1][ty],
                           tile[4 * tx + 2][ty], tile[4 * tx + 3][ty]);
    *(float4*)&outb[(size_t)(ht + ty) * LSEQ + lt + 4 * tx] = o;
}

__global__ __launch_bounds__(256) void k_transpose_bwd(const float* __restrict__ in,  // (B,H,L)
                                                       float* __restrict__ out)       // (B,L,H)
{
    __shared__ float tile[32][33];
    const int b  = blockIdx.z;
    const int lt = blockIdx.x * 32;
    const int ht = blockIdx.y * 32;
    const int tx = threadIdx.x;   // 8  (float4 over l)
    const int ty = threadIdx.y;   // 32 (h rows)
    const float* inb = in + (size_t)b * HCH * LSEQ;
    float* outb = out + (size_t)b * LSEQ * HCH;
    float4 v = *(const float4*)&inb[(size_t)(ht + ty) * LSEQ + lt + 4 * tx];
    tile[ty][4 * tx + 0] = v.x;
    tile[ty][4 * tx + 1] = v.y;
    tile[ty][4 * tx + 2] = v.z;
    tile[ty][4 * tx + 3] = v.w;
    __syncthreads();
    float4 o = make_float4(tile[4 * tx + 0][ty], tile[4 * tx + 1][ty],
                           tile[4 * tx + 2][ty], tile[4 * tx + 3][ty]);
    *(float4*)&outb[(size_t)(lt + ty) * HCH + ht + 4 * tx] = o;
}

// ----------------------------------------------------------- FFT convolve ---
__global__ __launch_bounds__(256) void k_fftconv(float* __restrict__ gut,       // [B][H][L]
                                                 const float* __restrict__ gKf, // [H][4096] float2
                                                 const float* __restrict__ gD)
{
    const int bid = blockIdx.x;        // 4096
    const int b = bid >> 9;            // 0..7
    const int h = bid & (HCH - 1);
    const int t = threadIdx.x;         // 256
    __shared__ float z[8704];

    float* row0 = gut + ((size_t)(b * HCH) + h) * LSEQ;
    float* row1 = gut + ((size_t)((b + 8) * HCH) + h) * LSEQ;

    float4 u0k[2], u1k[2];
#pragma unroll
    for (int i = 0; i < 2; ++i) {
        int q = t + 256 * i;
        u0k[i] = ((const float4*)row0)[q];
        u1k[i] = ((const float4*)row1)[q];
        int l = 4 * q;
        *(float2*)&z[WD(l + 0)] = make_float2(u0k[i].x, u1k[i].x);
        *(float2*)&z[WD(l + 1)] = make_float2(u0k[i].y, u1k[i].y);
        *(float2*)&z[WD(l + 2)] = make_float2(u0k[i].z, u1k[i].z);
        *(float2*)&z[WD(l + 3)] = make_float2(u0k[i].w, u1k[i].w);
    }
    __syncthreads();

    fft8_stage<0, false, true >(z, t); __syncthreads();
    fft8_stage<1, false, false>(z, t); __syncthreads();
    fft8_stage<2, false, false>(z, t); __syncthreads();
    mid_stage(z, (const float2*)gKf + (size_t)h * NF, t); __syncthreads();
    fft8_stage<2, true, false>(z, t); __syncthreads();
    fft8_stage<1, true, false>(z, t); __syncthreads();
    fft8_stage<0, true, true >(z, t); __syncthreads();

    const float sc = 1.0f / 4096.0f;
    const float Dh = gD[h];
#pragma unroll
    for (int i = 0; i < 2; ++i) {
        int q = t + 256 * i;
        int l = 4 * q;
        float2 z0 = *(float2*)&z[WD(l + 0)];
        float2 z1 = *(float2*)&z[WD(l + 1)];
        float2 z2 = *(float2*)&z[WD(l + 2)];
        float2 z3 = *(float2*)&z[WD(l + 3)];
        float4 o0 = make_float4(z0.x * sc + Dh * u0k[i].x, z1.x * sc + Dh * u0k[i].y,
                                z2.x * sc + Dh * u0k[i].z, z3.x * sc + Dh * u0k[i].w);
        float4 o1 = make_float4(z0.y * sc + Dh * u1k[i].x, z1.y * sc + Dh * u1k[i].y,
                                z2.y * sc + Dh * u1k[i].z, z3.y * sc + Dh * u1k[i].w);
        ((float4*)row0)[q] = o0;
        ((float4*)row1)[q] = o1;
    }
}

// ----------------------------------------------------------------- launch ---
extern "C" void kernel_launch(void* const* d_in, const int* in_sizes, int n_in,
                              void* d_out, int out_size, void* d_ws, size_t ws_size,
                              hipStream_t stream)
{
    const float* u      = (const float*)d_in[0];
    const float* lam_r  = (const float*)d_in[1];
    const float* lam_i  = (const float*)d_in[2];
    const float* Br     = (const float*)d_in[3];
    const float* Bi     = (const float*)d_in[4];
    const float* Cr     = (const float*)d_in[5];
    const float* Ci     = (const float*)d_in[6];
    const float* log_dt = (const float*)d_in[7];
    const float* Dv     = (const float*)d_in[8];

    float* gut = (float*)d_ws;     // 67.1 MB
    float* gKf = (float*)d_out;    // Kf scratch 16.8 MB, overwritten by final transpose

    k_kfft<<<HCH, 256, 0, stream>>>(lam_r, lam_i, Br, Bi, Cr, Ci, log_dt, gKf);
    k_transpose_fwd<<<dim3(LSEQ / 32, HCH / 32, BSZ), dim3(8, 32, 1), 0, stream>>>(u, gut);
    k_fftconv<<<BSZ / 2 * HCH, 256, 0, stream>>>(gut, gKf, Dv);
    k_transpose_bwd<<<dim3(LSEQ / 32, HCH / 32, BSZ), dim3(8, 32, 1), 0, stream>>>(gut, (float*)d_out);
}

// Round 4
// 238.185 us; speedup vs baseline: 6.3295x; 1.0260x over previous
//
#include <hip/hip_runtime.h>
#include <hip/hip_bf16.h>

// S4D layer: B=16, L=2048, H=512, N=64, fp32.
// Round 4: same radix-8 FFT-conv algorithm as R3, restructured for occupancy:
//  - 512-thread blocks, 1 butterfly per thread per stage (was 256 thr x 2)
//  - k_kfft also 512 threads (K-gen split 4 pts/thread)
//  - 64x64-tile transposes, float4 global both sides, conflict-free LDS
// ws: gut 67.1 MB. d_out doubles as Kf scratch (16.8 MB) until final transpose.

#define BSZ 16
#define LSEQ 2048
#define HCH 512
#define NST 64
#define NF 4096

// complex i -> word offset (pad 2 words every 16 complex)
__device__ __forceinline__ int WD(int i) { return 2 * i + ((i >> 4) << 1); }

__device__ __forceinline__ float2 cadd(float2 a, float2 b) { return make_float2(a.x + b.x, a.y + b.y); }
__device__ __forceinline__ float2 csub(float2 a, float2 b) { return make_float2(a.x - b.x, a.y - b.y); }
__device__ __forceinline__ float2 cmul(float2 a, float c, float s) {
    return make_float2(a.x * c - a.y * s, a.x * s + a.y * c);
}
__device__ __forceinline__ float2 cmul2(float2 a, float2 b) {
    return make_float2(a.x * b.x - a.y * b.y, a.x * b.y + a.y * b.x);
}

__device__ __forceinline__ void sincos_red(float a, float* s, float* c) {
    double ad = (double)a;
    double q = rint(ad * 0.15915494309189535);
    float r = (float)(ad - q * 6.283185307179586);
    __sincosf(r, s, c);
}

template <bool INV>
__device__ __forceinline__ void dft8_tail(float2 t0, float2 t1, float2 t2, float2 t3,
                                          float2 t4, float2 t5, float2 t6, float2 t7,
                                          float2& A0, float2& A1, float2& A2, float2& A3,
                                          float2& A4, float2& A5, float2& A6, float2& A7)
{
    const float S = 0.70710678118654752f;
    float2 u0 = cadd(t0, t2), u2 = csub(t0, t2);
    float2 u1 = cadd(t1, t3), u3 = csub(t1, t3);
    A0 = cadd(u0, u1); A4 = csub(u0, u1);
    if constexpr (!INV) {
        A2 = make_float2(u2.x + u3.y, u2.y - u3.x);
        A6 = make_float2(u2.x - u3.y, u2.y + u3.x);
    } else {
        A2 = make_float2(u2.x - u3.y, u2.y + u3.x);
        A6 = make_float2(u2.x + u3.y, u2.y - u3.x);
    }
    float2 b0 = t4, b1, b2, b3;
    if constexpr (!INV) {
        b1 = make_float2(S * (t5.x + t5.y), S * (t5.y - t5.x));
        b2 = make_float2(t6.y, -t6.x);
        b3 = make_float2(S * (t7.y - t7.x), -S * (t7.x + t7.y));
    } else {
        b1 = make_float2(S * (t5.x - t5.y), S * (t5.y + t5.x));
        b2 = make_float2(-t6.y, t6.x);
        b3 = make_float2(-S * (t7.x + t7.y), S * (t7.x - t7.y));
    }
    float2 v0 = cadd(b0, b2), v2 = csub(b0, b2);
    float2 v1 = cadd(b1, b3), v3 = csub(b1, b3);
    A1 = cadd(v0, v1); A5 = csub(v0, v1);
    if constexpr (!INV) {
        A3 = make_float2(v2.x + v3.y, v2.y - v3.x);
        A7 = make_float2(v2.x - v3.y, v2.y + v3.x);
    } else {
        A3 = make_float2(v2.x - v3.y, v2.y + v3.x);
        A7 = make_float2(v2.x + v3.y, v2.y - v3.x);
    }
}

// One radix-8 stage; NT threads, 4096/8/NT butterflies per thread.
template <int SIDX, bool INV, bool HALF, int NT>
__device__ __forceinline__ void fft8_stage(float* z, int t)
{
    constexpr int lgQ = 9 - 3 * SIDX;
    constexpr int Q = 1 << lgQ;
    constexpr int ITERS = 512 / NT;
    const float asc = -1.5339807878856412e-3f * (float)(1 << (3 * SIDX));
#pragma unroll
    for (int it = 0; it < ITERS; ++it) {
        const int bb = t + NT * it;
        const int j = bb & (Q - 1);
        const int base = ((bb >> lgQ) << (lgQ + 3)) + j;
        float s1, c1;
        __sincosf(asc * (float)j, &s1, &c1);
        if constexpr (INV) s1 = -s1;
        const float c2 = c1 * c1 - s1 * s1, s2 = 2.f * c1 * s1;
        const float c3 = c1 * c2 - s1 * s2, s3 = c1 * s2 + s1 * c2;
        const float c4 = c2 * c2 - s2 * s2, s4 = 2.f * c2 * s2;
        const float c5 = c2 * c3 - s2 * s3, s5 = c2 * s3 + s2 * c3;
        const float c6 = c3 * c3 - s3 * s3, s6 = 2.f * c3 * s3;
        const float c7 = c3 * c4 - s3 * s4, s7 = c3 * s4 + s3 * c4;
        float2 a0 = *(float2*)&z[WD(base + 0 * Q)];
        float2 a1 = *(float2*)&z[WD(base + 1 * Q)];
        float2 a2 = *(float2*)&z[WD(base + 2 * Q)];
        float2 a3 = *(float2*)&z[WD(base + 3 * Q)];
        float2 a4, a5, a6, a7;
        if constexpr (!(HALF && !INV)) {
            a4 = *(float2*)&z[WD(base + 4 * Q)];
            a5 = *(float2*)&z[WD(base + 5 * Q)];
            a6 = *(float2*)&z[WD(base + 6 * Q)];
            a7 = *(float2*)&z[WD(base + 7 * Q)];
        }
        if constexpr (INV) {
            a1 = cmul(a1, c1, s1); a2 = cmul(a2, c2, s2); a3 = cmul(a3, c3, s3);
            a4 = cmul(a4, c4, s4); a5 = cmul(a5, c5, s5); a6 = cmul(a6, c6, s6);
            a7 = cmul(a7, c7, s7);
        }
        float2 t0, t1, t2, t3, t4, t5, t6, t7;
        if constexpr (HALF && !INV) {
            t0 = a0; t4 = a0; t1 = a1; t5 = a1; t2 = a2; t6 = a2; t3 = a3; t7 = a3;
        } else {
            t0 = cadd(a0, a4); t4 = csub(a0, a4);
            t1 = cadd(a1, a5); t5 = csub(a1, a5);
            t2 = cadd(a2, a6); t6 = csub(a2, a6);
            t3 = cadd(a3, a7); t7 = csub(a3, a7);
        }
        float2 A0, A1, A2, A3, A4, A5, A6, A7;
        dft8_tail<INV>(t0, t1, t2, t3, t4, t5, t6, t7, A0, A1, A2, A3, A4, A5, A6, A7);
        if constexpr (!INV) {
            A1 = cmul(A1, c1, s1); A2 = cmul(A2, c2, s2); A3 = cmul(A3, c3, s3);
            A4 = cmul(A4, c4, s4); A5 = cmul(A5, c5, s5); A6 = cmul(A6, c6, s6);
            A7 = cmul(A7, c7, s7);
        }
        *(float2*)&z[WD(base + 0 * Q)] = A0;
        *(float2*)&z[WD(base + 1 * Q)] = A1;
        *(float2*)&z[WD(base + 2 * Q)] = A2;
        *(float2*)&z[WD(base + 3 * Q)] = A3;
        if constexpr (!(HALF && INV)) {
            *(float2*)&z[WD(base + 4 * Q)] = A4;
            *(float2*)&z[WD(base + 5 * Q)] = A5;
            *(float2*)&z[WD(base + 6 * Q)] = A6;
            *(float2*)&z[WD(base + 7 * Q)] = A7;
        }
    }
}

// fused: fwd stage3 (Q=1) + pointwise *Kf + inv stage3, in registers
template <int NT>
__device__ __forceinline__ void mid_stage(float* z, const float2* __restrict__ kf, int t)
{
    constexpr int ITERS = 512 / NT;
#pragma unroll
    for (int it = 0; it < ITERS; ++it) {
        const int bb = t + NT * it;
        const int base = bb * 8;
        float2 a[8];
#pragma unroll
        for (int r = 0; r < 8; ++r) a[r] = *(float2*)&z[WD(base + r)];
        float2 t0 = cadd(a[0], a[4]), t4 = csub(a[0], a[4]);
        float2 t1 = cadd(a[1], a[5]), t5 = csub(a[1], a[5]);
        float2 t2 = cadd(a[2], a[6]), t6 = csub(a[2], a[6]);
        float2 t3 = cadd(a[3], a[7]), t7 = csub(a[3], a[7]);
        float2 A0, A1, A2, A3, A4, A5, A6, A7;
        dft8_tail<false>(t0, t1, t2, t3, t4, t5, t6, t7, A0, A1, A2, A3, A4, A5, A6, A7);
        const float2* kp = kf + base;
        A0 = cmul2(A0, kp[0]); A1 = cmul2(A1, kp[1]);
        A2 = cmul2(A2, kp[2]); A3 = cmul2(A3, kp[3]);
        A4 = cmul2(A4, kp[4]); A5 = cmul2(A5, kp[5]);
        A6 = cmul2(A6, kp[6]); A7 = cmul2(A7, kp[7]);
        t0 = cadd(A0, A4); t4 = csub(A0, A4);
        t1 = cadd(A1, A5); t5 = csub(A1, A5);
        t2 = cadd(A2, A6); t6 = csub(A2, A6);
        t3 = cadd(A3, A7); t7 = csub(A3, A7);
        float2 X0, X1, X2, X3, X4, X5, X6, X7;
        dft8_tail<true>(t0, t1, t2, t3, t4, t5, t6, t7, X0, X1, X2, X3, X4, X5, X6, X7);
        *(float2*)&z[WD(base + 0)] = X0;
        *(float2*)&z[WD(base + 1)] = X1;
        *(float2*)&z[WD(base + 2)] = X2;
        *(float2*)&z[WD(base + 3)] = X3;
        *(float2*)&z[WD(base + 4)] = X4;
        *(float2*)&z[WD(base + 5)] = X5;
        *(float2*)&z[WD(base + 6)] = X6;
        *(float2*)&z[WD(base + 7)] = X7;
    }
}

// ------------------------------------------------- K table + forward FFT ---
__global__ __launch_bounds__(512, 4) void k_kfft(const float* __restrict__ lam_r,
                                                 const float* __restrict__ lam_i,
                                                 const float* __restrict__ Br,
                                                 const float* __restrict__ Bi,
                                                 const float* __restrict__ Cr,
                                                 const float* __restrict__ Ci,
                                                 const float* __restrict__ log_dt,
                                                 float* __restrict__ gKf)  // [H][4096] float2
{
    const int h = blockIdx.x;
    const int t = threadIdx.x;  // 512
    __shared__ float z[8704];
    __shared__ float sWr[NST], sWi[NST], sAr[NST], sAi[NST], sDr[NST], sDi[NST];

    if (t < NST) {
        const int n = t;
        float lr = lam_r[n], li = lam_i[n];
        float dt = __expf(log_dt[h]);
        float dar = dt * lr;
        float dai = dt * li;
        float e = __expf(dar);
        float sn, cs; sincos_red(dai, &sn, &cs);
        float Ar = e * cs, Ai = e * sn;
        float nr = Ar - 1.0f, ni = Ai;
        float br = Br[h * NST + n], bi = Bi[h * NST + n];
        float tr = br * nr - bi * ni;
        float ti = br * ni + bi * nr;
        float dr = lr + 1e-8f, di = li;
        float den = dr * dr + di * di;
        float bbr = (tr * dr + ti * di) / den;
        float bbi = (ti * dr - tr * di) / den;
        float cr = Cr[h * NST + n], ci = Ci[h * NST + n];
        sWr[n] = cr * bbr - ci * bbi;
        sWi[n] = cr * bbi + ci * bbr;
        sAr[n] = Ar; sAi[n] = Ai;
        sDr[n] = dar; sDi[n] = dai;
    }
    __syncthreads();

    const int l0 = t * 4;
    float acc[4];
#pragma unroll
    for (int k = 0; k < 4; ++k) acc[k] = 0.0f;
    const float fl0 = (float)l0;
    for (int n = 0; n < NST; ++n) {
        float dar = sDr[n], dai = sDi[n];
        float ang = dai * fl0;
        float sn, cs; sincos_red(ang, &sn, &cs);
        float e = __expf(dar * fl0);
        float pr = e * cs, pi = e * sn;
        float Ar = sAr[n], Ai = sAi[n];
        float wr = sWr[n], wi = sWi[n];
#pragma unroll
        for (int k = 0; k < 4; ++k) {
            acc[k] += wr * pr - wi * pi;
            float npr = pr * Ar - pi * Ai;
            pi = pr * Ai + pi * Ar;
            pr = npr;
        }
    }
#pragma unroll
    for (int k = 0; k < 4; ++k)
        *(float2*)&z[WD(l0 + k)] = make_float2(acc[k], 0.0f);
    __syncthreads();

    fft8_stage<0, false, true , 512>(z, t); __syncthreads();
    fft8_stage<1, false, false, 512>(z, t); __syncthreads();
    fft8_stage<2, false, false, 512>(z, t); __syncthreads();
    fft8_stage<3, false, false, 512>(z, t); __syncthreads();

    float2* out = (float2*)gKf + (size_t)h * NF;
#pragma unroll
    for (int i = 0; i < 8; ++i) {
        int idx = t + 512 * i;
        out[idx] = *(float2*)&z[WD(idx)];
    }
}

// -------------------------------------------------------------- transposes ---
// 64x64 tiles, 256 threads (16x16), float4 global both sides.
__global__ __launch_bounds__(256) void k_transpose_fwd(const float* __restrict__ in,  // (B,L,H)
                                                       float* __restrict__ out)       // (B,H,L)
{
    __shared__ float tile[64][65];
    const int b  = blockIdx.z;
    const int lt = blockIdx.x * 64;
    const int ht = blockIdx.y * 64;
    const int tx = threadIdx.x;   // 16
    const int ty = threadIdx.y;   // 16
    const float* inb = in + (size_t)b * LSEQ * HCH;
    float* outb = out + (size_t)b * HCH * LSEQ;
#pragma unroll
    for (int i = 0; i < 4; ++i) {
        int r = ty + 16 * i;
        float4 v = *(const float4*)&inb[(size_t)(lt + r) * HCH + ht + 4 * tx];
        tile[r][4 * tx + 0] = v.x;
        tile[r][4 * tx + 1] = v.y;
        tile[r][4 * tx + 2] = v.z;
        tile[r][4 * tx + 3] = v.w;
    }
    __syncthreads();
#pragma unroll
    for (int i = 0; i < 4; ++i) {
        int rp = ty + 16 * i;
        float4 o = make_float4(tile[4 * tx + 0][rp], tile[4 * tx + 1][rp],
                               tile[4 * tx + 2][rp], tile[4 * tx + 3][rp]);
        *(float4*)&outb[(size_t)(ht + rp) * LSEQ + lt + 4 * tx] = o;
    }
}

__global__ __launch_bounds__(256) void k_transpose_bwd(const float* __restrict__ in,  // (B,H,L)
                                                       float* __restrict__ out)       // (B,L,H)
{
    __shared__ float tile[64][65];
    const int b  = blockIdx.z;
    const int lt = blockIdx.x * 64;
    const int ht = blockIdx.y * 64;
    const int tx = threadIdx.x;
    const int ty = threadIdx.y;
    const float* inb = in + (size_t)b * HCH * LSEQ;
    float* outb = out + (size_t)b * LSEQ * HCH;
#pragma unroll
    for (int i = 0; i < 4; ++i) {
        int r = ty + 16 * i;
        float4 v = *(const float4*)&inb[(size_t)(ht + r) * LSEQ + lt + 4 * tx];
        tile[r][4 * tx + 0] = v.x;
        tile[r][4 * tx + 1] = v.y;
        tile[r][4 * tx + 2] = v.z;
        tile[r][4 * tx + 3] = v.w;
    }
    __syncthreads();
#pragma unroll
    for (int i = 0; i < 4; ++i) {
        int rp = ty + 16 * i;
        float4 o = make_float4(tile[4 * tx + 0][rp], tile[4 * tx + 1][rp],
                               tile[4 * tx + 2][rp], tile[4 * tx + 3][rp]);
        *(float4*)&outb[(size_t)(lt + rp) * HCH + ht + 4 * tx] = o;
    }
}

// ----------------------------------------------------------- FFT convolve ---
__global__ __launch_bounds__(512, 4) void k_fftconv(float* __restrict__ gut,       // [B][H][L]
                                                    const float* __restrict__ gKf, // [H][4096] float2
                                                    const float* __restrict__ gD)
{
    const int bid = blockIdx.x;        // 4096
    const int b = bid >> 9;            // 0..7
    const int h = bid & (HCH - 1);
    const int t = threadIdx.x;         // 512
    __shared__ float z[8704];

    float* row0 = gut + ((size_t)(b * HCH) + h) * LSEQ;
    float* row1 = gut + ((size_t)((b + 8) * HCH) + h) * LSEQ;

    float4 u0k = ((const float4*)row0)[t];
    float4 u1k = ((const float4*)row1)[t];
    {
        int l = 4 * t;
        *(float2*)&z[WD(l + 0)] = make_float2(u0k.x, u1k.x);
        *(float2*)&z[WD(l + 1)] = make_float2(u0k.y, u1k.y);
        *(float2*)&z[WD(l + 2)] = make_float2(u0k.z, u1k.z);
        *(float2*)&z[WD(l + 3)] = make_float2(u0k.w, u1k.w);
    }
    __syncthreads();

    fft8_stage<0, false, true , 512>(z, t); __syncthreads();
    fft8_stage<1, false, false, 512>(z, t); __syncthreads();
    fft8_stage<2, false, false, 512>(z, t); __syncthreads();
    mid_stage<512>(z, (const float2*)gKf + (size_t)h * NF, t); __syncthreads();
    fft8_stage<2, true, false, 512>(z, t); __syncthreads();
    fft8_stage<1, true, false, 512>(z, t); __syncthreads();
    fft8_stage<0, true, true , 512>(z, t); __syncthreads();

    const float sc = 1.0f / 4096.0f;
    const float Dh = gD[h];
    {
        int l = 4 * t;
        float2 z0 = *(float2*)&z[WD(l + 0)];
        float2 z1 = *(float2*)&z[WD(l + 1)];
        float2 z2 = *(float2*)&z[WD(l + 2)];
        float2 z3 = *(float2*)&z[WD(l + 3)];
        float4 o0 = make_float4(z0.x * sc + Dh * u0k.x, z1.x * sc + Dh * u0k.y,
                                z2.x * sc + Dh * u0k.z, z3.x * sc + Dh * u0k.w);
        float4 o1 = make_float4(z0.y * sc + Dh * u1k.x, z1.y * sc + Dh * u1k.y,
                                z2.y * sc + Dh * u1k.z, z3.y * sc + Dh * u1k.w);
        ((float4*)row0)[t] = o0;
        ((float4*)row1)[t] = o1;
    }
}

// ----------------------------------------------------------------- launch ---
extern "C" void kernel_launch(void* const* d_in, const int* in_sizes, int n_in,
                              void* d_out, int out_size, void* d_ws, size_t ws_size,
                              hipStream_t stream)
{
    const float* u      = (const float*)d_in[0];
    const float* lam_r  = (const float*)d_in[1];
    const float* lam_i  = (const float*)d_in[2];
    const float* Br     = (const float*)d_in[3];
    const float* Bi     = (const float*)d_in[4];
    const float* Cr     = (const float*)d_in[5];
    const float* Ci     = (const float*)d_in[6];
    const float* log_dt = (const float*)d_in[7];
    const float* Dv     = (const float*)d_in[8];

    float* gut = (float*)d_ws;     // 67.1 MB
    float* gKf = (float*)d_out;    // Kf scratch 16.8 MB, overwritten by final transpose

    k_kfft<<<HCH, 512, 0, stream>>>(lam_r, lam_i, Br, Bi, Cr, Ci, log_dt, gKf);
    k_transpose_fwd<<<dim3(LSEQ / 64, HCH / 64, BSZ), dim3(16, 16, 1), 0, stream>>>(u, gut);
    k_fftconv<<<BSZ / 2 * HCH, 512, 0, stream>>>(gut, gKf, Dv);
    k_transpose_bwd<<<dim3(LSEQ / 64, HCH / 64, BSZ), dim3(16, 16, 1), 0, stream>>>(gut, (float*)d_out);
}

// Round 5
// 229.083 us; speedup vs baseline: 6.5809x; 1.0397x over previous
//
#include <hip/hip_runtime.h>
#include <hip/hip_bf16.h>

// S4D layer: B=16, L=2048, H=512, N=64, fp32.
// Round 5: pipeline restructure (conv untouched):
//   k_kgen:   time-domain K -> ws scratch, 1024 blocks (4x parallelism of old)
//   k_fused:  [F: 512 blocks] K-FFT -> Kf (d_out scratch)  overlapped with
//             [T: 4096 blocks] transpose (B,L,H)->(B,H,L) -> ws
//   k_fftconv: unchanged (R4, 82 us)
//   k_transpose_bwd: unchanged
// ws: gut 67.1 MB + gKt 4.2 MB = 71.3 MB. Kf (16.8 MB) in d_out until tbwd.

#define BSZ 16
#define LSEQ 2048
#define HCH 512
#define NST 64
#define NF 4096

// complex i -> word offset (pad 2 words every 16 complex)
__device__ __forceinline__ int WD(int i) { return 2 * i + ((i >> 4) << 1); }

__device__ __forceinline__ float2 cadd(float2 a, float2 b) { return make_float2(a.x + b.x, a.y + b.y); }
__device__ __forceinline__ float2 csub(float2 a, float2 b) { return make_float2(a.x - b.x, a.y - b.y); }
__device__ __forceinline__ float2 cmul(float2 a, float c, float s) {
    return make_float2(a.x * c - a.y * s, a.x * s + a.y * c);
}
__device__ __forceinline__ float2 cmul2(float2 a, float2 b) {
    return make_float2(a.x * b.x - a.y * b.y, a.x * b.y + a.y * b.x);
}

__device__ __forceinline__ void sincos_red(float a, float* s, float* c) {
    double ad = (double)a;
    double q = rint(ad * 0.15915494309189535);
    float r = (float)(ad - q * 6.283185307179586);
    __sincosf(r, s, c);
}

template <bool INV>
__device__ __forceinline__ void dft8_tail(float2 t0, float2 t1, float2 t2, float2 t3,
                                          float2 t4, float2 t5, float2 t6, float2 t7,
                                          float2& A0, float2& A1, float2& A2, float2& A3,
                                          float2& A4, float2& A5, float2& A6, float2& A7)
{
    const float S = 0.70710678118654752f;
    float2 u0 = cadd(t0, t2), u2 = csub(t0, t2);
    float2 u1 = cadd(t1, t3), u3 = csub(t1, t3);
    A0 = cadd(u0, u1); A4 = csub(u0, u1);
    if constexpr (!INV) {
        A2 = make_float2(u2.x + u3.y, u2.y - u3.x);
        A6 = make_float2(u2.x - u3.y, u2.y + u3.x);
    } else {
        A2 = make_float2(u2.x - u3.y, u2.y + u3.x);
        A6 = make_float2(u2.x + u3.y, u2.y - u3.x);
    }
    float2 b0 = t4, b1, b2, b3;
    if constexpr (!INV) {
        b1 = make_float2(S * (t5.x + t5.y), S * (t5.y - t5.x));
        b2 = make_float2(t6.y, -t6.x);
        b3 = make_float2(S * (t7.y - t7.x), -S * (t7.x + t7.y));
    } else {
        b1 = make_float2(S * (t5.x - t5.y), S * (t5.y + t5.x));
        b2 = make_float2(-t6.y, t6.x);
        b3 = make_float2(-S * (t7.x + t7.y), S * (t7.x - t7.y));
    }
    float2 v0 = cadd(b0, b2), v2 = csub(b0, b2);
    float2 v1 = cadd(b1, b3), v3 = csub(b1, b3);
    A1 = cadd(v0, v1); A5 = csub(v0, v1);
    if constexpr (!INV) {
        A3 = make_float2(v2.x + v3.y, v2.y - v3.x);
        A7 = make_float2(v2.x - v3.y, v2.y + v3.x);
    } else {
        A3 = make_float2(v2.x - v3.y, v2.y + v3.x);
        A7 = make_float2(v2.x + v3.y, v2.y - v3.x);
    }
}

// One radix-8 stage; NT threads, 4096/8/NT butterflies per thread.
template <int SIDX, bool INV, bool HALF, int NT>
__device__ __forceinline__ void fft8_stage(float* z, int t)
{
    constexpr int lgQ = 9 - 3 * SIDX;
    constexpr int Q = 1 << lgQ;
    constexpr int ITERS = 512 / NT;
    const float asc = -1.5339807878856412e-3f * (float)(1 << (3 * SIDX));
#pragma unroll
    for (int it = 0; it < ITERS; ++it) {
        const int bb = t + NT * it;
        const int j = bb & (Q - 1);
        const int base = ((bb >> lgQ) << (lgQ + 3)) + j;
        float s1, c1;
        __sincosf(asc * (float)j, &s1, &c1);
        if constexpr (INV) s1 = -s1;
        const float c2 = c1 * c1 - s1 * s1, s2 = 2.f * c1 * s1;
        const float c3 = c1 * c2 - s1 * s2, s3 = c1 * s2 + s1 * c2;
        const float c4 = c2 * c2 - s2 * s2, s4 = 2.f * c2 * s2;
        const float c5 = c2 * c3 - s2 * s3, s5 = c2 * s3 + s2 * c3;
        const float c6 = c3 * c3 - s3 * s3, s6 = 2.f * c3 * s3;
        const float c7 = c3 * c4 - s3 * s4, s7 = c3 * s4 + s3 * c4;
        float2 a0 = *(float2*)&z[WD(base + 0 * Q)];
        float2 a1 = *(float2*)&z[WD(base + 1 * Q)];
        float2 a2 = *(float2*)&z[WD(base + 2 * Q)];
        float2 a3 = *(float2*)&z[WD(base + 3 * Q)];
        float2 a4, a5, a6, a7;
        if constexpr (!(HALF && !INV)) {
            a4 = *(float2*)&z[WD(base + 4 * Q)];
            a5 = *(float2*)&z[WD(base + 5 * Q)];
            a6 = *(float2*)&z[WD(base + 6 * Q)];
            a7 = *(float2*)&z[WD(base + 7 * Q)];
        }
        if constexpr (INV) {
            a1 = cmul(a1, c1, s1); a2 = cmul(a2, c2, s2); a3 = cmul(a3, c3, s3);
            a4 = cmul(a4, c4, s4); a5 = cmul(a5, c5, s5); a6 = cmul(a6, c6, s6);
            a7 = cmul(a7, c7, s7);
        }
        float2 t0, t1, t2, t3, t4, t5, t6, t7;
        if constexpr (HALF && !INV) {
            t0 = a0; t4 = a0; t1 = a1; t5 = a1; t2 = a2; t6 = a2; t3 = a3; t7 = a3;
        } else {
            t0 = cadd(a0, a4); t4 = csub(a0, a4);
            t1 = cadd(a1, a5); t5 = csub(a1, a5);
            t2 = cadd(a2, a6); t6 = csub(a2, a6);
            t3 = cadd(a3, a7); t7 = csub(a3, a7);
        }
        float2 A0, A1, A2, A3, A4, A5, A6, A7;
        dft8_tail<INV>(t0, t1, t2, t3, t4, t5, t6, t7, A0, A1, A2, A3, A4, A5, A6, A7);
        if constexpr (!INV) {
            A1 = cmul(A1, c1, s1); A2 = cmul(A2, c2, s2); A3 = cmul(A3, c3, s3);
            A4 = cmul(A4, c4, s4); A5 = cmul(A5, c5, s5); A6 = cmul(A6, c6, s6);
            A7 = cmul(A7, c7, s7);
        }
        *(float2*)&z[WD(base + 0 * Q)] = A0;
        *(float2*)&z[WD(base + 1 * Q)] = A1;
        *(float2*)&z[WD(base + 2 * Q)] = A2;
        *(float2*)&z[WD(base + 3 * Q)] = A3;
        if constexpr (!(HALF && INV)) {
            *(float2*)&z[WD(base + 4 * Q)] = A4;
            *(float2*)&z[WD(base + 5 * Q)] = A5;
            *(float2*)&z[WD(base + 6 * Q)] = A6;
            *(float2*)&z[WD(base + 7 * Q)] = A7;
        }
    }
}

// fused: fwd stage3 (Q=1) + pointwise *Kf + inv stage3, in registers
template <int NT>
__device__ __forceinline__ void mid_stage(float* z, const float2* __restrict__ kf, int t)
{
    constexpr int ITERS = 512 / NT;
#pragma unroll
    for (int it = 0; it < ITERS; ++it) {
        const int bb = t + NT * it;
        const int base = bb * 8;
        float2 a[8];
#pragma unroll
        for (int r = 0; r < 8; ++r) a[r] = *(float2*)&z[WD(base + r)];
        float2 t0 = cadd(a[0], a[4]), t4 = csub(a[0], a[4]);
        float2 t1 = cadd(a[1], a[5]), t5 = csub(a[1], a[5]);
        float2 t2 = cadd(a[2], a[6]), t6 = csub(a[2], a[6]);
        float2 t3 = cadd(a[3], a[7]), t7 = csub(a[3], a[7]);
        float2 A0, A1, A2, A3, A4, A5, A6, A7;
        dft8_tail<false>(t0, t1, t2, t3, t4, t5, t6, t7, A0, A1, A2, A3, A4, A5, A6, A7);
        const float2* kp = kf + base;
        A0 = cmul2(A0, kp[0]); A1 = cmul2(A1, kp[1]);
        A2 = cmul2(A2, kp[2]); A3 = cmul2(A3, kp[3]);
        A4 = cmul2(A4, kp[4]); A5 = cmul2(A5, kp[5]);
        A6 = cmul2(A6, kp[6]); A7 = cmul2(A7, kp[7]);
        t0 = cadd(A0, A4); t4 = csub(A0, A4);
        t1 = cadd(A1, A5); t5 = csub(A1, A5);
        t2 = cadd(A2, A6); t6 = csub(A2, A6);
        t3 = cadd(A3, A7); t7 = csub(A3, A7);
        float2 X0, X1, X2, X3, X4, X5, X6, X7;
        dft8_tail<true>(t0, t1, t2, t3, t4, t5, t6, t7, X0, X1, X2, X3, X4, X5, X6, X7);
        *(float2*)&z[WD(base + 0)] = X0;
        *(float2*)&z[WD(base + 1)] = X1;
        *(float2*)&z[WD(base + 2)] = X2;
        *(float2*)&z[WD(base + 3)] = X3;
        *(float2*)&z[WD(base + 4)] = X4;
        *(float2*)&z[WD(base + 5)] = X5;
        *(float2*)&z[WD(base + 6)] = X6;
        *(float2*)&z[WD(base + 7)] = X7;
    }
}

// ------------------------------------------------------- time-domain K ---
// 1024 blocks: h = bid>>1, half = bid&1; 256 threads, 4 l per thread.
__global__ __launch_bounds__(256) void k_kgen(const float* __restrict__ lam_r,
                                              const float* __restrict__ lam_i,
                                              const float* __restrict__ Br,
                                              const float* __restrict__ Bi,
                                              const float* __restrict__ Cr,
                                              const float* __restrict__ Ci,
                                              const float* __restrict__ log_dt,
                                              float* __restrict__ gKt)  // [H][2048]
{
    const int h = blockIdx.x >> 1;
    const int half = blockIdx.x & 1;
    const int t = threadIdx.x;  // 256
    __shared__ float sWr[NST], sWi[NST], sAr[NST], sAi[NST], sDr[NST], sDi[NST];

    if (t < NST) {
        const int n = t;
        float lr = lam_r[n], li = lam_i[n];
        float dt = __expf(log_dt[h]);
        float dar = dt * lr;
        float dai = dt * li;
        float e = __expf(dar);
        float sn, cs; sincos_red(dai, &sn, &cs);
        float Ar = e * cs, Ai = e * sn;
        float nr = Ar - 1.0f, ni = Ai;
        float br = Br[h * NST + n], bi = Bi[h * NST + n];
        float tr = br * nr - bi * ni;
        float ti = br * ni + bi * nr;
        float dr = lr + 1e-8f, di = li;
        float den = dr * dr + di * di;
        float bbr = (tr * dr + ti * di) / den;
        float bbi = (ti * dr - tr * di) / den;
        float cr = Cr[h * NST + n], ci = Ci[h * NST + n];
        sWr[n] = cr * bbr - ci * bbi;
        sWi[n] = cr * bbi + ci * bbr;
        sAr[n] = Ar; sAi[n] = Ai;
        sDr[n] = dar; sDi[n] = dai;
    }
    __syncthreads();

    const int l0 = half * 1024 + 4 * t;
    float acc[4] = {0.f, 0.f, 0.f, 0.f};
    const float fl0 = (float)l0;
    for (int n = 0; n < NST; ++n) {
        float dar = sDr[n], dai = sDi[n];
        float ang = dai * fl0;
        float sn, cs; sincos_red(ang, &sn, &cs);
        float e = __expf(dar * fl0);
        float pr = e * cs, pi = e * sn;
        float Ar = sAr[n], Ai = sAi[n];
        float wr = sWr[n], wi = sWi[n];
#pragma unroll
        for (int k = 0; k < 4; ++k) {
            acc[k] += wr * pr - wi * pi;
            float npr = pr * Ar - pi * Ai;
            pi = pr * Ai + pi * Ar;
            pr = npr;
        }
    }
    *(float4*)&gKt[(size_t)h * LSEQ + l0] = make_float4(acc[0], acc[1], acc[2], acc[3]);
}

// --------------------- fused: K-FFT (512 blocks) + fwd transpose (4096) ---
__global__ __launch_bounds__(512) void k_fused(const float* __restrict__ gKt,  // [H][2048]
                                               float* __restrict__ gKf,        // [H][4096] float2
                                               const float* __restrict__ u,    // (B,L,H)
                                               float* __restrict__ gut)        // (B,H,L)
{
    const int bid = blockIdx.x;
    const int t = threadIdx.x;  // 512
    __shared__ float lds[8704];

    if (bid < HCH) {
        // ---- role F: forward FFT of K row ----
        const int h = bid;
        float4 kv = ((const float4*)(gKt + (size_t)h * LSEQ))[t];
        int l = 4 * t;
        *(float2*)&lds[WD(l + 0)] = make_float2(kv.x, 0.f);
        *(float2*)&lds[WD(l + 1)] = make_float2(kv.y, 0.f);
        *(float2*)&lds[WD(l + 2)] = make_float2(kv.z, 0.f);
        *(float2*)&lds[WD(l + 3)] = make_float2(kv.w, 0.f);
        __syncthreads();
        fft8_stage<0, false, true , 512>(lds, t); __syncthreads();
        fft8_stage<1, false, false, 512>(lds, t); __syncthreads();
        fft8_stage<2, false, false, 512>(lds, t); __syncthreads();
        fft8_stage<3, false, false, 512>(lds, t); __syncthreads();
        float2* out = (float2*)gKf + (size_t)h * NF;
#pragma unroll
        for (int i = 0; i < 8; ++i) {
            int idx = t + 512 * i;
            out[idx] = *(float2*)&lds[WD(idx)];
        }
    } else {
        // ---- role T: 64x64 transpose tile, 512 threads ----
        float (*tile)[65] = (float (*)[65])lds;
        const int tid2 = bid - HCH;
        const int b  = tid2 >> 8;
        const int ht = ((tid2 >> 5) & 7) * 64;
        const int lt = (tid2 & 31) * 64;
        const int tx = t & 15;   // float4 column
        const int ty = t >> 4;   // 0..31
        const float* inb = u + (size_t)b * LSEQ * HCH;
        float* outb = gut + (size_t)b * HCH * LSEQ;
#pragma unroll
        for (int i = 0; i < 2; ++i) {
            int r = ty + 32 * i;
            float4 v = *(const float4*)&inb[(size_t)(lt + r) * HCH + ht + 4 * tx];
            tile[r][4 * tx + 0] = v.x;
            tile[r][4 * tx + 1] = v.y;
            tile[r][4 * tx + 2] = v.z;
            tile[r][4 * tx + 3] = v.w;
        }
        __syncthreads();
#pragma unroll
        for (int i = 0; i < 2; ++i) {
            int rp = ty + 32 * i;
            float4 o = make_float4(tile[4 * tx + 0][rp], tile[4 * tx + 1][rp],
                                   tile[4 * tx + 2][rp], tile[4 * tx + 3][rp]);
            *(float4*)&outb[(size_t)(ht + rp) * LSEQ + lt + 4 * tx] = o;
        }
    }
}

// -------------------------------------------------------- bwd transpose ---
__global__ __launch_bounds__(256) void k_transpose_bwd(const float* __restrict__ in,  // (B,H,L)
                                                       float* __restrict__ out)       // (B,L,H)
{
    __shared__ float tile[64][65];
    const int b  = blockIdx.z;
    const int lt = blockIdx.x * 64;
    const int ht = blockIdx.y * 64;
    const int tx = threadIdx.x;
    const int ty = threadIdx.y;
    const float* inb = in + (size_t)b * HCH * LSEQ;
    float* outb = out + (size_t)b * LSEQ * HCH;
#pragma unroll
    for (int i = 0; i < 4; ++i) {
        int r = ty + 16 * i;
        float4 v = *(const float4*)&inb[(size_t)(ht + r) * LSEQ + lt + 4 * tx];
        tile[r][4 * tx + 0] = v.x;
        tile[r][4 * tx + 1] = v.y;
        tile[r][4 * tx + 2] = v.z;
        tile[r][4 * tx + 3] = v.w;
    }
    __syncthreads();
#pragma unroll
    for (int i = 0; i < 4; ++i) {
        int rp = ty + 16 * i;
        float4 o = make_float4(tile[4 * tx + 0][rp], tile[4 * tx + 1][rp],
                               tile[4 * tx + 2][rp], tile[4 * tx + 3][rp]);
        *(float4*)&outb[(size_t)(lt + rp) * HCH + ht + 4 * tx] = o;
    }
}

// ----------------------------------------------------------- FFT convolve ---
__global__ __launch_bounds__(512, 4) void k_fftconv(float* __restrict__ gut,       // [B][H][L]
                                                    const float* __restrict__ gKf, // [H][4096] float2
                                                    const float* __restrict__ gD)
{
    const int bid = blockIdx.x;        // 4096
    const int b = bid >> 9;            // 0..7
    const int h = bid & (HCH - 1);
    const int t = threadIdx.x;         // 512
    __shared__ float z[8704];

    float* row0 = gut + ((size_t)(b * HCH) + h) * LSEQ;
    float* row1 = gut + ((size_t)((b + 8) * HCH) + h) * LSEQ;

    float4 u0k = ((const float4*)row0)[t];
    float4 u1k = ((const float4*)row1)[t];
    {
        int l = 4 * t;
        *(float2*)&z[WD(l + 0)] = make_float2(u0k.x, u1k.x);
        *(float2*)&z[WD(l + 1)] = make_float2(u0k.y, u1k.y);
        *(float2*)&z[WD(l + 2)] = make_float2(u0k.z, u1k.z);
        *(float2*)&z[WD(l + 3)] = make_float2(u0k.w, u1k.w);
    }
    __syncthreads();

    fft8_stage<0, false, true , 512>(z, t); __syncthreads();
    fft8_stage<1, false, false, 512>(z, t); __syncthreads();
    fft8_stage<2, false, false, 512>(z, t); __syncthreads();
    mid_stage<512>(z, (const float2*)gKf + (size_t)h * NF, t); __syncthreads();
    fft8_stage<2, true, false, 512>(z, t); __syncthreads();
    fft8_stage<1, true, false, 512>(z, t); __syncthreads();
    fft8_stage<0, true, true , 512>(z, t); __syncthreads();

    const float sc = 1.0f / 4096.0f;
    const float Dh = gD[h];
    {
        int l = 4 * t;
        float2 z0 = *(float2*)&z[WD(l + 0)];
        float2 z1 = *(float2*)&z[WD(l + 1)];
        float2 z2 = *(float2*)&z[WD(l + 2)];
        float2 z3 = *(float2*)&z[WD(l + 3)];
        float4 o0 = make_float4(z0.x * sc + Dh * u0k.x, z1.x * sc + Dh * u0k.y,
                                z2.x * sc + Dh * u0k.z, z3.x * sc + Dh * u0k.w);
        float4 o1 = make_float4(z0.y * sc + Dh * u1k.x, z1.y * sc + Dh * u1k.y,
                                z2.y * sc + Dh * u1k.z, z3.y * sc + Dh * u1k.w);
        ((float4*)row0)[t] = o0;
        ((float4*)row1)[t] = o1;
    }
}

// ----------------------------------------------------------------- launch ---
extern "C" void kernel_launch(void* const* d_in, const int* in_sizes, int n_in,
                              void* d_out, int out_size, void* d_ws, size_t ws_size,
                              hipStream_t stream)
{
    const float* u      = (const float*)d_in[0];
    const float* lam_r  = (const float*)d_in[1];
    const float* lam_i  = (const float*)d_in[2];
    const float* Br     = (const float*)d_in[3];
    const float* Bi     = (const float*)d_in[4];
    const float* Cr     = (const float*)d_in[5];
    const float* Ci     = (const float*)d_in[6];
    const float* log_dt = (const float*)d_in[7];
    const float* Dv     = (const float*)d_in[8];

    float* gut = (float*)d_ws;                               // 67.1 MB
    float* gKt = (float*)d_ws + (size_t)BSZ * HCH * LSEQ;    // 4.2 MB
    float* gKf = (float*)d_out;                              // 16.8 MB scratch until tbwd

    k_kgen<<<2 * HCH, 256, 0, stream>>>(lam_r, lam_i, Br, Bi, Cr, Ci, log_dt, gKt);
    k_fused<<<HCH + 4096, 512, 0, stream>>>(gKt, gKf, u, gut);
    k_fftconv<<<BSZ / 2 * HCH, 512, 0, stream>>>(gut, gKf, Dv);
    k_transpose_bwd<<<dim3(LSEQ / 64, HCH / 64, BSZ), dim3(16, 16, 1), 0, stream>>>(gut, (float*)d_out);
}